// Round 2
// baseline (1399.093 us; speedup 1.0000x reference)
//
#include <hip/hip_runtime.h>
#include <hip/hip_bf16.h>
#include <cmath>
#include <cstdint>

#define B_ 2
#define N_ 8192
#define H_ 12
#define D_ 64
#define E_ 768
#define M_ (B_*N_)   // 16384

typedef __attribute__((ext_vector_type(8))) short short8;
typedef __attribute__((ext_vector_type(4))) short short4v;
typedef __attribute__((ext_vector_type(4))) float float4v;

__device__ inline short f2b(float f) {
  union { float f; unsigned u; } x; x.f = f;
  unsigned r = (x.u + 0x7fffu + ((x.u >> 16) & 1u)) >> 16;
  return (short)r;
}
__device__ inline float b2f(short s) {
  union { unsigned u; float f; } x; x.u = ((unsigned)(unsigned short)s) << 16;
  return x.f;
}
// x ~= hi + lo, representation error <= 2^-16 relative
__device__ inline void split2(float f, short& h, short& l) {
  h = f2b(f);
  l = f2b(f - b2f(h));
}

#define MFMA(a, b, c) __builtin_amdgcn_mfma_f32_16x16x32_bf16((a), (b), (c), 0, 0, 0)

// C[m][n] = sum_k A[m][k]*W[n][k] + bias[n], split-precision (bf16 hi/lo x 4 products)
// A: fp32 [16384x768] (A_PAIR=false) or bf16 hi/lo pair arrays (A_PAIR=true)
// Out: hi/lo bf16 pair (OUT_PAIR=true) or fp32 (false)
template<bool A_PAIR, bool OUT_PAIR>
__global__ __launch_bounds__(256) void gemm_xwT(const void* __restrict__ Ap,
    const short* __restrict__ Alo, const float* __restrict__ W,
    const float* __restrict__ bias, void* __restrict__ OutH, short* __restrict__ OutL)
{
  __shared__ short Ash[128 * 40], Asl[128 * 40];
  __shared__ short Wsh[128 * 40], Wsl[128 * 40];
  const int tid = threadIdx.x;
  const int m0 = blockIdx.y * 128;
  const int n0 = blockIdx.x * 128;
  const int w = tid >> 6, lane = tid & 63, quad = lane >> 4, l16 = lane & 15;
  const int wr = w >> 1, wc = w & 1;

  float4v acc[4][4];
#pragma unroll
  for (int a = 0; a < 4; ++a)
#pragma unroll
    for (int c = 0; c < 4; ++c) acc[a][c] = (float4v)0.0f;

  for (int kt = 0; kt < 24; ++kt) {
    const int k0 = kt * 32;
#pragma unroll
    for (int p = 0; p < 4; ++p) {
      int idx = tid + p * 256;          // 1024 tasks: 128 rows x 8 chunks of 4
      int row = idx >> 3, c4 = (idx & 7) * 4;
      short4v avh, avl;
      if constexpr (A_PAIR) {
        avh = *(const short4v*)((const short*)Ap + (size_t)(m0 + row) * E_ + k0 + c4);
        avl = *(const short4v*)(Alo + (size_t)(m0 + row) * E_ + k0 + c4);
      } else {
        float4v t = *(const float4v*)((const float*)Ap + (size_t)(m0 + row) * E_ + k0 + c4);
        short hh, ll;
        split2(t.x, hh, ll); avh.x = hh; avl.x = ll;
        split2(t.y, hh, ll); avh.y = hh; avl.y = ll;
        split2(t.z, hh, ll); avh.z = hh; avl.z = ll;
        split2(t.w, hh, ll); avh.w = hh; avl.w = ll;
      }
      *(short4v*)&Ash[row * 40 + c4] = avh;
      *(short4v*)&Asl[row * 40 + c4] = avl;
      float4v tw = *(const float4v*)(W + (size_t)(n0 + row) * E_ + k0 + c4);
      short4v wvh, wvl; short hh, ll;
      split2(tw.x, hh, ll); wvh.x = hh; wvl.x = ll;
      split2(tw.y, hh, ll); wvh.y = hh; wvl.y = ll;
      split2(tw.z, hh, ll); wvh.z = hh; wvl.z = ll;
      split2(tw.w, hh, ll); wvh.w = hh; wvl.w = ll;
      *(short4v*)&Wsh[row * 40 + c4] = wvh;
      *(short4v*)&Wsl[row * 40 + c4] = wvl;
    }
    __syncthreads();

    short8 afh[4], afl[4], bfh[4], bfl[4];
#pragma unroll
    for (int rt = 0; rt < 4; ++rt) {
      afh[rt] = *(const short8*)&Ash[(wr * 64 + rt * 16 + l16) * 40 + quad * 8];
      afl[rt] = *(const short8*)&Asl[(wr * 64 + rt * 16 + l16) * 40 + quad * 8];
    }
#pragma unroll
    for (int ct = 0; ct < 4; ++ct) {
      bfh[ct] = *(const short8*)&Wsh[(wc * 64 + ct * 16 + l16) * 40 + quad * 8];
      bfl[ct] = *(const short8*)&Wsl[(wc * 64 + ct * 16 + l16) * 40 + quad * 8];
    }
#pragma unroll
    for (int rt = 0; rt < 4; ++rt)
#pragma unroll
      for (int ct = 0; ct < 4; ++ct) {
        float4v a = acc[rt][ct];
        a = MFMA(afh[rt], bfh[ct], a);
        a = MFMA(afh[rt], bfl[ct], a);
        a = MFMA(afl[rt], bfh[ct], a);
        a = MFMA(afl[rt], bfl[ct], a);
        acc[rt][ct] = a;
      }
    __syncthreads();
  }

#pragma unroll
  for (int ct = 0; ct < 4; ++ct) {
    int n = n0 + wc * 64 + ct * 16 + l16;
    float bv = bias[n];
#pragma unroll
    for (int rt = 0; rt < 4; ++rt) {
#pragma unroll
      for (int i = 0; i < 4; ++i) {
        int m = m0 + wr * 64 + rt * 16 + quad * 4 + i;
        float v = acc[rt][ct][i] + bv;
        if constexpr (OUT_PAIR) {
          short hh, ll; split2(v, hh, ll);
          ((short*)OutH)[(size_t)m * E_ + n] = hh;
          OutL[(size_t)m * E_ + n] = ll;
        } else {
          ((float*)OutH)[(size_t)m * E_ + n] = v;
        }
      }
    }
  }
}

// Flash attention over the dilated gathers, split-precision throughout.
// g=0: r=1,s=2048,nseg=4,heads 0..3; g=1: r=2,s=4096,nseg=2,heads 4..7;
// g=2: r=4,s=8192,nseg=1,heads 8..11. All 2048 gathered positions.
// Block = 128 q-rows (4 waves x 32), 64 KV tiles of 32.
__global__ __launch_bounds__(256) void attn_kernel(
    const short* __restrict__ qh, const short* __restrict__ ql,
    const short* __restrict__ kh, const short* __restrict__ kl,
    const short* __restrict__ vh, const short* __restrict__ vl,
    float* __restrict__ attn_out, float* __restrict__ sums)
{
  __shared__ short Ksh[32 * 72], Ksl[32 * 72];
  __shared__ short Vsh[32 * 72], Vsl[32 * 72];
  __shared__ short Psh[4][32 * 40], Psl[4][32 * 40];

  int bid = blockIdx.x;
  int g, t;
  if (bid < 512)      { g = 0; t = bid; }
  else if (bid < 768) { g = 1; t = bid - 512; }
  else                { g = 2; t = bid - 768; }
  const int qt = t & 15; t >>= 4;
  const int hg = t & 3; t >>= 2;
  const int nseg = 4 >> g;
  const int seg = t & (nseg - 1);
  const int b = t / nseg;
  const int r = 1 << g;
  const int off = g & (r - 1);          // 0,1,2
  const int h = g * 4 + hg;
  const int segbase = seg * (2048 << g);

  const int tid = threadIdx.x;
  const int w = tid >> 6, lane = tid & 63, quad = lane >> 4, l16 = lane & 15;

  // Q fragments (A layout: m = l16, k = quad*8+j [+32*ks])
  short8 qfh[2][2], qfl[2][2];
#pragma unroll
  for (int rt = 0; rt < 2; ++rt) {
    int j = qt * 128 + w * 32 + rt * 16 + l16;
    int pos = segbase + off + j * r;
    size_t base = ((size_t)(b * N_ + pos) * H_ + h) * D_;
#pragma unroll
    for (int ks = 0; ks < 2; ++ks) {
      qfh[rt][ks] = *(const short8*)(qh + base + ks * 32 + quad * 8);
      qfl[rt][ks] = *(const short8*)(ql + base + ks * 32 + quad * 8);
    }
  }

  float4v o[2][4];
  float mrow[2][4], lrow[2][4];
#pragma unroll
  for (int rt = 0; rt < 2; ++rt) {
#pragma unroll
    for (int dt = 0; dt < 4; ++dt) o[rt][dt] = (float4v)0.0f;
#pragma unroll
    for (int i = 0; i < 4; ++i) { mrow[rt][i] = -INFINITY; lrow[rt][i] = 0.f; }
  }

  for (int kt = 0; kt < 64; ++kt) {
    // stage K,V hi/lo: 256 tasks = 32 rows x 8 chunks of 8
    {
      int row = tid >> 3, c8 = (tid & 7) * 8;
      int posk = segbase + off + (kt * 32 + row) * r;
      size_t gb = ((size_t)(b * N_ + posk) * H_ + h) * D_ + c8;
      *(short8*)&Ksh[row * 72 + c8] = *(const short8*)(kh + gb);
      *(short8*)&Ksl[row * 72 + c8] = *(const short8*)(kl + gb);
      *(short8*)&Vsh[row * 72 + c8] = *(const short8*)(vh + gb);
      *(short8*)&Vsl[row * 72 + c8] = *(const short8*)(vl + gb);
    }
    __syncthreads();

    // S = Q K^T (4-product split)
    float4v sc[2][2];
#pragma unroll
    for (int ct = 0; ct < 2; ++ct) {
      const int kb0 = (ct * 16 + l16) * 72 + quad * 8;
      short8 kh0 = *(const short8*)&Ksh[kb0];
      short8 kh1 = *(const short8*)&Ksh[kb0 + 32];
      short8 kl0 = *(const short8*)&Ksl[kb0];
      short8 kl1 = *(const short8*)&Ksl[kb0 + 32];
#pragma unroll
      for (int rt = 0; rt < 2; ++rt) {
        float4v a = (float4v)0.0f;
        a = MFMA(qfh[rt][0], kh0, a); a = MFMA(qfh[rt][1], kh1, a);
        a = MFMA(qfh[rt][0], kl0, a); a = MFMA(qfh[rt][1], kl1, a);
        a = MFMA(qfl[rt][0], kh0, a); a = MFMA(qfl[rt][1], kh1, a);
        a = MFMA(qfl[rt][0], kl0, a); a = MFMA(qfl[rt][1], kl1, a);
        sc[rt][ct] = a * 0.125f;       // 1/sqrt(64)
      }
    }

    // online softmax; rows live in 16 lanes of a quad
#pragma unroll
    for (int rt = 0; rt < 2; ++rt) {
#pragma unroll
      for (int i = 0; i < 4; ++i) {
        float mx = fmaxf(sc[rt][0][i], sc[rt][1][i]);
#pragma unroll
        for (int d_ = 1; d_ < 16; d_ <<= 1) mx = fmaxf(mx, __shfl_xor(mx, d_, 64));
        float mnew = fmaxf(mrow[rt][i], mx);
        float alpha = __expf(mrow[rt][i] - mnew);
        mrow[rt][i] = mnew;
        float rs = 0.f;
#pragma unroll
        for (int ct = 0; ct < 2; ++ct) {
          float p = __expf(sc[rt][ct][i] - mnew);
          sc[rt][ct][i] = p;
          rs += p;
        }
#pragma unroll
        for (int d_ = 1; d_ < 16; d_ <<= 1) rs += __shfl_xor(rs, d_, 64);
        lrow[rt][i] = lrow[rt][i] * alpha + rs;
#pragma unroll
        for (int dt = 0; dt < 4; ++dt) o[rt][dt][i] *= alpha;
      }
      // P: C-layout -> LDS row-major hi/lo, wave-private slab
#pragma unroll
      for (int ct = 0; ct < 2; ++ct)
#pragma unroll
        for (int i = 0; i < 4; ++i) {
          short hh, ll; split2(sc[rt][ct][i], hh, ll);
          Psh[w][(rt * 16 + quad * 4 + i) * 40 + ct * 16 + l16] = hh;
          Psl[w][(rt * 16 + quad * 4 + i) * 40 + ct * 16 + l16] = ll;
        }
    }

    // O += P V (K dim = 32 kv rows -> single mfma per product)
    short8 pfh[2], pfl[2];
#pragma unroll
    for (int rt = 0; rt < 2; ++rt) {
      pfh[rt] = *(const short8*)&Psh[w][(rt * 16 + l16) * 40 + quad * 8];
      pfl[rt] = *(const short8*)&Psl[w][(rt * 16 + l16) * 40 + quad * 8];
    }
#pragma unroll
    for (int dt = 0; dt < 4; ++dt) {
      short8 vfh, vfl;
#pragma unroll
      for (int j = 0; j < 8; ++j) {
        vfh[j] = Vsh[(quad * 8 + j) * 72 + dt * 16 + l16];
        vfl[j] = Vsl[(quad * 8 + j) * 72 + dt * 16 + l16];
      }
#pragma unroll
      for (int rt = 0; rt < 2; ++rt) {
        float4v a = o[rt][dt];
        a = MFMA(pfh[rt], vfh, a);
        a = MFMA(pfh[rt], vfl, a);
        a = MFMA(pfl[rt], vfh, a);
        a = MFMA(pfl[rt], vfl, a);
        o[rt][dt] = a;
      }
    }
    __syncthreads();
  }

  // epilogue: divide by denom, scatter fp32, partial sums
  float sacc[4] = {0.f, 0.f, 0.f, 0.f};
#pragma unroll
  for (int rt = 0; rt < 2; ++rt) {
#pragma unroll
    for (int i = 0; i < 4; ++i) {
      float inv_l = 1.0f / lrow[rt][i];
      int j = qt * 128 + w * 32 + rt * 16 + quad * 4 + i;
      int pos = segbase + off + j * r;
      float* dst = attn_out + ((size_t)(b * N_ + pos) * H_ + h) * D_;
#pragma unroll
      for (int dt = 0; dt < 4; ++dt) {
        float v = o[rt][dt][i] * inv_l;
        dst[dt * 16 + l16] = v;
        sacc[dt] += v;
      }
    }
  }
#pragma unroll
  for (int dt = 0; dt < 4; ++dt) {
    float v = sacc[dt];
    v += __shfl_xor(v, 16, 64);
    v += __shfl_xor(v, 32, 64);
    if (quad == 0)
      atomicAdd(&sums[(size_t)b * E_ + h * D_ + dt * 16 + l16], v);
  }
}

// xnorm = covered ? attn/sums : 0, emitted as bf16 hi/lo pair
__global__ __launch_bounds__(256) void normalize_kernel(const float* __restrict__ attn,
    const float* __restrict__ sums, short* __restrict__ xnh, short* __restrict__ xnl)
{
  size_t e4 = ((size_t)blockIdx.x * 256 + threadIdx.x) * 4;
  int e = (int)(e4 % E_);
  int nn = (int)((e4 / E_) % N_);
  int b = (int)(e4 / ((size_t)E_ * N_));
  int g = e >> 8;                  // 256 channels (4 heads x 64) per group
  int r = 1 << g;
  int off = g & (r - 1);
  short4v oh, ol;
  if ((nn & (r - 1)) == off) {
    float4v a = *(const float4v*)(attn + e4);
    const float* sp = sums + (size_t)b * E_ + e;
    short hh, ll;
    split2(a.x / sp[0], hh, ll); oh.x = hh; ol.x = ll;
    split2(a.y / sp[1], hh, ll); oh.y = hh; ol.y = ll;
    split2(a.z / sp[2], hh, ll); oh.z = hh; ol.z = ll;
    split2(a.w / sp[3], hh, ll); oh.w = hh; ol.w = ll;
  } else {
    oh = (short4v)(short)0;
    ol = (short4v)(short)0;
  }
  *(short4v*)&xnh[e4] = oh;
  *(short4v*)&xnl[e4] = ol;
}

extern "C" void kernel_launch(void* const* d_in, const int* in_sizes, int n_in,
                              void* d_out, int out_size, void* d_ws, size_t ws_size,
                              hipStream_t stream)
{
  const float* query = (const float*)d_in[0];
  const float* key_  = (const float*)d_in[1];
  const float* value = (const float*)d_in[2];
  const float* Wq = (const float*)d_in[3];
  const float* bq = (const float*)d_in[4];
  const float* Wk = (const float*)d_in[5];
  const float* bk = (const float*)d_in[6];
  const float* Wv = (const float*)d_in[7];
  const float* bv = (const float*)d_in[8];
  const float* Wo = (const float*)d_in[9];
  const float* bo = (const float*)d_in[10];

  char* ws = (char*)d_ws;
  const size_t szbf = (size_t)M_ * E_ * 2;   // 25165824
  const size_t szf  = (size_t)M_ * E_ * 4;   // 50331648
  short* qh_ = (short*)(ws);
  short* ql_ = (short*)(ws + 1 * szbf);
  short* kh_ = (short*)(ws + 2 * szbf);
  short* kl_ = (short*)(ws + 3 * szbf);
  short* vh_ = (short*)(ws + 4 * szbf);
  short* vl_ = (short*)(ws + 5 * szbf);
  float* attn = (float*)(ws + 6 * szbf);
  float* sums = (float*)(ws + 6 * szbf + szf);
  short* xnh = kh_;                           // k dead after attn_kernel
  short* xnl = kl_;

  hipMemsetAsync(sums, 0, (size_t)B_ * E_ * sizeof(float), stream);

  dim3 gg(6, 128), gb(256);
  gemm_xwT<false, true><<<gg, gb, 0, stream>>>(query, nullptr, Wq, bq, qh_, ql_);
  gemm_xwT<false, true><<<gg, gb, 0, stream>>>(key_,  nullptr, Wk, bk, kh_, kl_);
  gemm_xwT<false, true><<<gg, gb, 0, stream>>>(value, nullptr, Wv, bv, vh_, vl_);
  attn_kernel<<<896, 256, 0, stream>>>(qh_, ql_, kh_, kl_, vh_, vl_, attn, sums);
  normalize_kernel<<<12288, 256, 0, stream>>>(attn, sums, xnh, xnl);
  gemm_xwT<true, false><<<gg, gb, 0, stream>>>(xnh, xnl, Wo, bo, d_out, nullptr);
}

// Round 3
// 948.692 us; speedup vs baseline: 1.4748x; 1.4748x over previous
//
#include <hip/hip_runtime.h>
#include <hip/hip_bf16.h>
#include <cmath>
#include <cstdint>

#define B_ 2
#define N_ 8192
#define H_ 12
#define D_ 64
#define E_ 768
#define M_ (B_*N_)   // 16384

typedef __attribute__((ext_vector_type(8))) short short8;
typedef __attribute__((ext_vector_type(4))) short short4v;
typedef __attribute__((ext_vector_type(4))) float float4v;

__device__ inline short f2b(float f) {
  union { float f; unsigned u; } x; x.f = f;
  unsigned r = (x.u + 0x7fffu + ((x.u >> 16) & 1u)) >> 16;
  return (short)r;
}
__device__ inline float b2f(short s) {
  union { unsigned u; float f; } x; x.u = ((unsigned)(unsigned short)s) << 16;
  return x.f;
}
// x ~= hi + lo, representation error <= ~2^-16 relative
__device__ inline void split2(float f, short& h, short& l) {
  h = f2b(f);
  l = f2b(f - b2f(h));
}

#define MFMA(a, b, c) __builtin_amdgcn_mfma_f32_16x16x32_bf16((a), (b), (c), 0, 0, 0)

// fp32 -> bf16 hi/lo planes, 4 elems/thread
__global__ __launch_bounds__(256) void split_kernel(const float* __restrict__ src,
    short* __restrict__ hi, short* __restrict__ lo, int count4)
{
  int i = blockIdx.x * 256 + threadIdx.x;
  if (i >= count4) return;
  float4v t = ((const float4v*)src)[i];
  short4v h4, l4; short hh, ll;
  split2(t.x, hh, ll); h4.x = hh; l4.x = ll;
  split2(t.y, hh, ll); h4.y = hh; l4.y = ll;
  split2(t.z, hh, ll); h4.z = hh; l4.z = ll;
  split2(t.w, hh, ll); h4.w = hh; l4.w = ll;
  ((short4v*)hi)[i] = h4;
  ((short4v*)lo)[i] = l4;
}

// C[m][n] = sum_k A[m][k]*W[n][k] + bias[n], split precision (3 products, lo*lo dropped)
// A: fp32 (A_PAIR=false, split in-kernel) or bf16 hi/lo pair (A_PAIR=true)
// W: pre-split bf16 hi/lo planes [768x768]
template<bool A_PAIR, bool OUT_PAIR>
__global__ __launch_bounds__(256) void gemm_xwT(const void* __restrict__ Ap,
    const short* __restrict__ Alo, const short* __restrict__ Wh,
    const short* __restrict__ Wl, const float* __restrict__ bias,
    void* __restrict__ OutH, short* __restrict__ OutL)
{
  __shared__ short Ash[128 * 40], Asl[128 * 40];
  __shared__ short Wsh[128 * 40], Wsl[128 * 40];
  const int tid = threadIdx.x;
  const int m0 = blockIdx.y * 128;
  const int n0 = blockIdx.x * 128;
  const int w = tid >> 6, lane = tid & 63, quad = lane >> 4, l16 = lane & 15;
  const int wr = w >> 1, wc = w & 1;

  float4v acc[4][4];
#pragma unroll
  for (int a = 0; a < 4; ++a)
#pragma unroll
    for (int c = 0; c < 4; ++c) acc[a][c] = (float4v)0.0f;

  for (int kt = 0; kt < 24; ++kt) {
    const int k0 = kt * 32;
#pragma unroll
    for (int p = 0; p < 4; ++p) {
      int idx = tid + p * 256;          // 1024 tasks: 128 rows x 8 chunks of 4
      int row = idx >> 3, c4 = (idx & 7) * 4;
      short4v avh, avl;
      if constexpr (A_PAIR) {
        avh = *(const short4v*)((const short*)Ap + (size_t)(m0 + row) * E_ + k0 + c4);
        avl = *(const short4v*)(Alo + (size_t)(m0 + row) * E_ + k0 + c4);
      } else {
        float4v t = *(const float4v*)((const float*)Ap + (size_t)(m0 + row) * E_ + k0 + c4);
        short hh, ll;
        split2(t.x, hh, ll); avh.x = hh; avl.x = ll;
        split2(t.y, hh, ll); avh.y = hh; avl.y = ll;
        split2(t.z, hh, ll); avh.z = hh; avl.z = ll;
        split2(t.w, hh, ll); avh.w = hh; avl.w = ll;
      }
      *(short4v*)&Ash[row * 40 + c4] = avh;
      *(short4v*)&Asl[row * 40 + c4] = avl;
      *(short4v*)&Wsh[row * 40 + c4] = *(const short4v*)(Wh + (size_t)(n0 + row) * E_ + k0 + c4);
      *(short4v*)&Wsl[row * 40 + c4] = *(const short4v*)(Wl + (size_t)(n0 + row) * E_ + k0 + c4);
    }
    __syncthreads();

    short8 afh[4], afl[4], bfh[4], bfl[4];
#pragma unroll
    for (int rt = 0; rt < 4; ++rt) {
      afh[rt] = *(const short8*)&Ash[(wr * 64 + rt * 16 + l16) * 40 + quad * 8];
      afl[rt] = *(const short8*)&Asl[(wr * 64 + rt * 16 + l16) * 40 + quad * 8];
    }
#pragma unroll
    for (int ct = 0; ct < 4; ++ct) {
      bfh[ct] = *(const short8*)&Wsh[(wc * 64 + ct * 16 + l16) * 40 + quad * 8];
      bfl[ct] = *(const short8*)&Wsl[(wc * 64 + ct * 16 + l16) * 40 + quad * 8];
    }
#pragma unroll
    for (int rt = 0; rt < 4; ++rt)
#pragma unroll
      for (int ct = 0; ct < 4; ++ct) {
        float4v a = acc[rt][ct];
        a = MFMA(afh[rt], bfh[ct], a);
        a = MFMA(afh[rt], bfl[ct], a);
        a = MFMA(afl[rt], bfh[ct], a);
        acc[rt][ct] = a;
      }
    __syncthreads();
  }

#pragma unroll
  for (int ct = 0; ct < 4; ++ct) {
    int n = n0 + wc * 64 + ct * 16 + l16;
    float bv = bias[n];
#pragma unroll
    for (int rt = 0; rt < 4; ++rt) {
#pragma unroll
      for (int i = 0; i < 4; ++i) {
        int m = m0 + wr * 64 + rt * 16 + quad * 4 + i;
        float v = acc[rt][ct][i] + bv;
        if constexpr (OUT_PAIR) {
          short hh, ll; split2(v, hh, ll);
          ((short*)OutH)[(size_t)m * E_ + n] = hh;
          OutL[(size_t)m * E_ + n] = ll;
        } else {
          ((float*)OutH)[(size_t)m * E_ + n] = v;
        }
      }
    }
  }
}

// cumulative jj-extent offset per head: g=h>>2, ext=8192>>g
__device__ __host__ inline int hoff_of(int g, int hg) {
  return g == 0 ? hg * 8192 : (g == 1 ? 32768 + hg * 4096 : 49152 + hg * 2048);
}

// V [b][n][h][d] hi/lo -> gathered transposed Vg [b][h][d][jj] (jj = seg*2048 + j)
__global__ __launch_bounds__(256) void transpose_v(const short* __restrict__ vh,
    const short* __restrict__ vl, short* __restrict__ vgh, short* __restrict__ vgl)
{
  __shared__ short Lh[64 * 68], Ll[64 * 68];
  int bid = blockIdx.x;
  int b = 0;
  if (bid >= 896) { b = 1; bid -= 896; }
  int g, hg, tile;
  if (bid < 512)      { g = 0; hg = bid >> 7; tile = bid & 127; }
  else if (bid < 768) { g = 1; hg = (bid - 512) >> 6; tile = (bid - 512) & 63; }
  else                { g = 2; hg = (bid - 768) >> 5; tile = (bid - 768) & 31; }
  const int h = g * 4 + hg, r = 1 << g, off = g;   // off = i % r = g for g=0,1,2
  const int ext = 8192 >> g;
  const int jj0 = tile * 64, seg = jj0 >> 11, j0 = jj0 & 2047;
  const int n0 = seg * (2048 << g) + off + j0 * r;
  const int tid = threadIdx.x;

#pragma unroll
  for (int p = 0; p < 2; ++p) {
    int c = tid + p * 256;            // 512 chunks: 64 jj x 8 d-chunks
    int jr = c >> 3, c8 = (c & 7) * 8;
    size_t gsrc = ((size_t)(b * N_ + n0 + jr * r) * H_ + h) * D_ + c8;
    *(short8*)&Lh[jr * 68 + c8] = *(const short8*)(vh + gsrc);
    *(short8*)&Ll[jr * 68 + c8] = *(const short8*)(vl + gsrc);
  }
  __syncthreads();
  size_t basebh = ((size_t)b * 57344 + hoff_of(g, hg)) * 64;
#pragma unroll
  for (int p = 0; p < 2; ++p) {
    int c = tid + p * 256;            // 512 chunks: 64 d x 8 jj-chunks
    int dd = c >> 3, jc = (c & 7) * 8;
    short8 oh, ol;
#pragma unroll
    for (int u = 0; u < 8; ++u) {
      oh[u] = Lh[(jc + u) * 68 + dd];
      ol[u] = Ll[(jc + u) * 68 + dd];
    }
    size_t gdst = basebh + (size_t)dd * ext + jj0 + jc;
    *(short8*)(vgh + gdst) = oh;
    *(short8*)(vgl + gdst) = ol;
  }
}

// Flash attention, S^T = K*Q^T / O^T = V^T*P^T formulation, split precision.
// Block = 128 q-rows (4 waves x 32), 64 KV tiles of 32.
__global__ __launch_bounds__(256) void attn_kernel(
    const short* __restrict__ qh, const short* __restrict__ ql,
    const short* __restrict__ kh, const short* __restrict__ kl,
    const short* __restrict__ vgh, const short* __restrict__ vgl,
    float* __restrict__ attn_out, float* __restrict__ sums)
{
  __shared__ short Ksh[32 * 72], Ksl[32 * 72];
  __shared__ short Vth[64 * 40], Vtl[64 * 40];
  __shared__ short Psh[4][32 * 40], Psl[4][32 * 40];

  int bid = blockIdx.x;
  int g, t;
  if (bid < 512)      { g = 0; t = bid; }
  else if (bid < 768) { g = 1; t = bid - 512; }
  else                { g = 2; t = bid - 768; }
  const int qtile = t & 15; t >>= 4;
  const int hg = t & 3; t >>= 2;
  const int nseg = 4 >> g;
  const int seg = t & (nseg - 1);
  const int b = t / nseg;
  const int r = 1 << g;
  const int off = g;                    // i % r = g
  const int h = g * 4 + hg;
  const int segbase = seg * (2048 << g);
  const int ext = 8192 >> g;

  const int tid = threadIdx.x;
  const int w = tid >> 6, lane = tid & 63, quad = lane >> 4, l16 = lane & 15;

  const size_t vbase = ((size_t)b * 57344 + hoff_of(g, hg)) * 64 + (size_t)seg * 2048;

  // Q B-frags (n = l16 = q, k = quad*8+j [+32*ks])
  short8 qfh[2][2], qfl[2][2];
#pragma unroll
  for (int qt = 0; qt < 2; ++qt) {
    int j = qtile * 128 + w * 32 + qt * 16 + l16;
    int pos = segbase + off + j * r;
    size_t base = ((size_t)(b * N_ + pos) * H_ + h) * D_;
#pragma unroll
    for (int ks = 0; ks < 2; ++ks) {
      qfh[qt][ks] = *(const short8*)(qh + base + ks * 32 + quad * 8);
      qfl[qt][ks] = *(const short8*)(ql + base + ks * 32 + quad * 8);
    }
  }

  float4v o[4][2];                      // [dt][qt], O^T: row=d=quad*4+i, col=q=l16
  float mrow[2], lrow[2];
#pragma unroll
  for (int dt = 0; dt < 4; ++dt)
#pragma unroll
    for (int qt = 0; qt < 2; ++qt) o[dt][qt] = (float4v)0.0f;
  mrow[0] = mrow[1] = -INFINITY;
  lrow[0] = lrow[1] = 0.f;

  for (int kt = 0; kt < 64; ++kt) {
    // stage K (normal [kv][72]) + Vt (pre-transposed, [d][40])
    {
      int row = tid & 31, c8 = (tid >> 5) * 8;
      int posk = segbase + off + (kt * 32 + row) * r;
      size_t gb = ((size_t)(b * N_ + posk) * H_ + h) * D_ + c8;
      *(short8*)&Ksh[row * 72 + c8] = *(const short8*)(kh + gb);
      *(short8*)&Ksl[row * 72 + c8] = *(const short8*)(kl + gb);
      int dd = tid >> 2, kvc = (tid & 3) * 8;
      size_t vb = vbase + (size_t)dd * ext + kt * 32 + kvc;
      *(short8*)&Vth[dd * 40 + kvc] = *(const short8*)(vgh + vb);
      *(short8*)&Vtl[dd * 40 + kvc] = *(const short8*)(vgl + vb);
    }
    __syncthreads();

    // S^T = K*Q^T: A = K (m=kv), B = Q (n=q); 3-product split
    float4v sc[2][2];                   // [qt][kvt]
#pragma unroll
    for (int kvt = 0; kvt < 2; ++kvt) {
      const int kb = (kvt * 16 + l16) * 72 + quad * 8;
      short8 ah0 = *(const short8*)&Ksh[kb];
      short8 ah1 = *(const short8*)&Ksh[kb + 32];
      short8 al0 = *(const short8*)&Ksl[kb];
      short8 al1 = *(const short8*)&Ksl[kb + 32];
#pragma unroll
      for (int qt = 0; qt < 2; ++qt) {
        float4v a = (float4v)0.0f;
        a = MFMA(ah0, qfh[qt][0], a); a = MFMA(ah1, qfh[qt][1], a);
        a = MFMA(ah0, qfl[qt][0], a); a = MFMA(ah1, qfl[qt][1], a);
        a = MFMA(al0, qfh[qt][0], a); a = MFMA(al1, qfh[qt][1], a);
        sc[qt][kvt] = a * 0.125f;       // 1/sqrt(64)
      }
    }

    // online softmax: q = l16 (broadcast across quads after 2-shfl reduce)
#pragma unroll
    for (int qt = 0; qt < 2; ++qt) {
      float mx = sc[qt][0][0];
#pragma unroll
      for (int kvt = 0; kvt < 2; ++kvt)
#pragma unroll
        for (int i = 0; i < 4; ++i) mx = fmaxf(mx, sc[qt][kvt][i]);
      mx = fmaxf(mx, __shfl_xor(mx, 16, 64));
      mx = fmaxf(mx, __shfl_xor(mx, 32, 64));
      float mnew = fmaxf(mrow[qt], mx);
      float alpha = __expf(mrow[qt] - mnew);
      mrow[qt] = mnew;
      float rs = 0.f;
#pragma unroll
      for (int kvt = 0; kvt < 2; ++kvt)
#pragma unroll
        for (int i = 0; i < 4; ++i) {
          float p = __expf(sc[qt][kvt][i] - mnew);
          sc[qt][kvt][i] = p;
          rs += p;
        }
      rs += __shfl_xor(rs, 16, 64);
      rs += __shfl_xor(rs, 32, 64);
      lrow[qt] = lrow[qt] * alpha + rs;
#pragma unroll
      for (int dt = 0; dt < 4; ++dt) o[dt][qt] *= alpha;

      // P^T (C-layout) -> Ps[q][kv], packed pair writes
#pragma unroll
      for (int kvt = 0; kvt < 2; ++kvt)
#pragma unroll
        for (int c = 0; c < 2; ++c) {
          short h0, l0, h1, l1;
          split2(sc[qt][kvt][2 * c], h0, l0);
          split2(sc[qt][kvt][2 * c + 1], h1, l1);
          int ad = (qt * 16 + l16) * 40 + kvt * 16 + quad * 4 + 2 * c;
          *(unsigned*)&Psh[w][ad] = (unsigned)(unsigned short)h0 | ((unsigned)(unsigned short)h1 << 16);
          *(unsigned*)&Psl[w][ad] = (unsigned)(unsigned short)l0 | ((unsigned)(unsigned short)l1 << 16);
        }
    }

    // O^T += V^T * P^T: A = V^T from Vt (vector reads), B = P from Ps
    short8 pfh[2], pfl[2];
#pragma unroll
    for (int qt = 0; qt < 2; ++qt) {
      pfh[qt] = *(const short8*)&Psh[w][(qt * 16 + l16) * 40 + quad * 8];
      pfl[qt] = *(const short8*)&Psl[w][(qt * 16 + l16) * 40 + quad * 8];
    }
#pragma unroll
    for (int dt = 0; dt < 4; ++dt) {
      short8 vfh = *(const short8*)&Vth[(dt * 16 + l16) * 40 + quad * 8];
      short8 vfl = *(const short8*)&Vtl[(dt * 16 + l16) * 40 + quad * 8];
#pragma unroll
      for (int qt = 0; qt < 2; ++qt) {
        float4v a = o[dt][qt];
        a = MFMA(vfh, pfh[qt], a);
        a = MFMA(vfh, pfl[qt], a);
        a = MFMA(vfl, pfh[qt], a);
        o[dt][qt] = a;
      }
    }
    __syncthreads();
  }

  // epilogue: O^T lane holds q=l16, d=dt*16+quad*4+i -> float4 stores
  float4v sacc[4];
#pragma unroll
  for (int dt = 0; dt < 4; ++dt) sacc[dt] = (float4v)0.0f;
#pragma unroll
  for (int qt = 0; qt < 2; ++qt) {
    float inv_l = 1.0f / lrow[qt];
    int j = qtile * 128 + w * 32 + qt * 16 + l16;
    int pos = segbase + off + j * r;
    float* dst = attn_out + ((size_t)(b * N_ + pos) * H_ + h) * D_;
#pragma unroll
    for (int dt = 0; dt < 4; ++dt) {
      float4v v = o[dt][qt] * inv_l;
      *(float4v*)(dst + dt * 16 + quad * 4) = v;
      sacc[dt] += v;
    }
  }
#pragma unroll
  for (int dt = 0; dt < 4; ++dt) {
#pragma unroll
    for (int i = 0; i < 4; ++i) {
      float x = sacc[dt][i];
      x += __shfl_xor(x, 1, 64);
      x += __shfl_xor(x, 2, 64);
      x += __shfl_xor(x, 4, 64);
      x += __shfl_xor(x, 8, 64);
      if (l16 == 0)
        atomicAdd(&sums[(size_t)b * E_ + h * D_ + dt * 16 + quad * 4 + i], x);
    }
  }
}

// xnorm = covered ? attn/sums : 0, emitted as bf16 hi/lo pair
__global__ __launch_bounds__(256) void normalize_kernel(const float* __restrict__ attn,
    const float* __restrict__ sums, short* __restrict__ xnh, short* __restrict__ xnl)
{
  size_t e4 = ((size_t)blockIdx.x * 256 + threadIdx.x) * 4;
  int e = (int)(e4 % E_);
  int nn = (int)((e4 / E_) % N_);
  int b = (int)(e4 / ((size_t)E_ * N_));
  int g = e >> 8;                  // 256 channels (4 heads x 64) per group
  int r = 1 << g;
  int off = g & (r - 1);
  short4v oh, ol;
  if ((nn & (r - 1)) == off) {
    float4v a = *(const float4v*)(attn + e4);
    const float* sp = sums + (size_t)b * E_ + e;
    short hh, ll;
    split2(a.x / sp[0], hh, ll); oh.x = hh; ol.x = ll;
    split2(a.y / sp[1], hh, ll); oh.y = hh; ol.y = ll;
    split2(a.z / sp[2], hh, ll); oh.z = hh; ol.z = ll;
    split2(a.w / sp[3], hh, ll); oh.w = hh; ol.w = ll;
  } else {
    oh = (short4v)(short)0;
    ol = (short4v)(short)0;
  }
  *(short4v*)&xnh[e4] = oh;
  *(short4v*)&xnl[e4] = ol;
}

extern "C" void kernel_launch(void* const* d_in, const int* in_sizes, int n_in,
                              void* d_out, int out_size, void* d_ws, size_t ws_size,
                              hipStream_t stream)
{
  const float* query = (const float*)d_in[0];
  const float* key_  = (const float*)d_in[1];
  const float* value = (const float*)d_in[2];
  const float* Wq = (const float*)d_in[3];
  const float* bq = (const float*)d_in[4];
  const float* Wk = (const float*)d_in[5];
  const float* bk = (const float*)d_in[6];
  const float* Wv = (const float*)d_in[7];
  const float* bv = (const float*)d_in[8];
  const float* Wo = (const float*)d_in[9];
  const float* bo = (const float*)d_in[10];

  char* ws = (char*)d_ws;
  const size_t szbf = (size_t)M_ * E_ * 2;           // 25,165,824
  const size_t szvg = (size_t)2 * 57344 * 64 * 2;    // 14,680,064
  const size_t szw  = (size_t)E_ * E_ * 2;           // 1,179,648
  short* qh_ = (short*)(ws);
  short* ql_ = (short*)(ws + 1 * szbf);
  short* kh_ = (short*)(ws + 2 * szbf);
  short* kl_ = (short*)(ws + 3 * szbf);
  short* vh_ = (short*)(ws + 4 * szbf);
  short* vl_ = (short*)(ws + 5 * szbf);
  short* vgh = (short*)(ws + 6 * szbf);
  short* vgl = (short*)(ws + 6 * szbf + szvg);
  short* wsp = (short*)(ws + 6 * szbf + 2 * szvg);   // 8 planes of szw
  short* wqh = wsp + 0 * (szw / 2), *wql = wsp + 1 * (szw / 2);
  short* wkh = wsp + 2 * (szw / 2), *wkl = wsp + 3 * (szw / 2);
  short* wvh = wsp + 4 * (szw / 2), *wvl = wsp + 5 * (szw / 2);
  short* woh = wsp + 6 * (szw / 2), *wol = wsp + 7 * (szw / 2);
  float* sums = (float*)(ws + 6 * szbf + 2 * szvg + 8 * szw);
  float* attn = (float*)(ws + 4 * szbf);             // overlays vh/vl (dead after transpose)
  short* xnh = kh_;                                  // k dead after attn_kernel
  short* xnl = kl_;

  hipMemsetAsync(sums, 0, (size_t)B_ * E_ * sizeof(float), stream);

  const int wc4 = E_ * E_ / 4;                       // 147456
  split_kernel<<<(wc4 + 255) / 256, 256, 0, stream>>>(Wq, wqh, wql, wc4);
  split_kernel<<<(wc4 + 255) / 256, 256, 0, stream>>>(Wk, wkh, wkl, wc4);
  split_kernel<<<(wc4 + 255) / 256, 256, 0, stream>>>(Wv, wvh, wvl, wc4);
  split_kernel<<<(wc4 + 255) / 256, 256, 0, stream>>>(Wo, woh, wol, wc4);

  dim3 gg(6, 128), gb(256);
  gemm_xwT<false, true><<<gg, gb, 0, stream>>>(query, nullptr, wqh, wql, bq, qh_, ql_);
  gemm_xwT<false, true><<<gg, gb, 0, stream>>>(key_,  nullptr, wkh, wkl, bk, kh_, kl_);
  gemm_xwT<false, true><<<gg, gb, 0, stream>>>(value, nullptr, wvh, wvl, bv, vh_, vl_);
  transpose_v<<<1792, 256, 0, stream>>>(vh_, vl_, vgh, vgl);
  attn_kernel<<<896, 256, 0, stream>>>(qh_, ql_, kh_, kl_, vgh, vgl, attn, sums);
  normalize_kernel<<<12288, 256, 0, stream>>>(attn, sums, xnh, xnl);
  gemm_xwT<true, false><<<gg, gb, 0, stream>>>(xnh, xnl, woh, wol, bo, d_out, nullptr);
}

// Round 4
// 886.541 us; speedup vs baseline: 1.5781x; 1.0701x over previous
//
#include <hip/hip_runtime.h>
#include <hip/hip_bf16.h>
#include <cmath>
#include <cstdint>

#define B_ 2
#define N_ 8192
#define H_ 12
#define D_ 64
#define E_ 768
#define M_ (B_*N_)   // 16384

typedef __attribute__((ext_vector_type(8))) short short8;
typedef __attribute__((ext_vector_type(4))) short short4v;
typedef __attribute__((ext_vector_type(4))) float float4v;
typedef __attribute__((ext_vector_type(2))) unsigned uint2v;

__device__ inline short f2b(float f) {
  union { float f; unsigned u; } x; x.f = f;
  unsigned r = (x.u + 0x7fffu + ((x.u >> 16) & 1u)) >> 16;
  return (short)r;
}
__device__ inline float b2f(short s) {
  union { unsigned u; float f; } x; x.u = ((unsigned)(unsigned short)s) << 16;
  return x.f;
}
// full round-to-nearest split (cold paths): residual ~2^-18
__device__ inline void split2(float f, short& h, short& l) {
  h = f2b(f);
  l = f2b(f - b2f(h));
}
// RN hi (single rounding) + exact fp32 lo (hot GEMM staging): residual ~2^-17 after lo-trunc
__device__ inline void split_rn1(float f, unsigned& hi16, float& lo) {
  unsigned u = __float_as_uint(f);
  unsigned r = u + 0x7fffu + ((u >> 16) & 1u);
  hi16 = r >> 16;
  lo = f - __uint_as_float(hi16 << 16);
}
__device__ inline unsigned pack_trunc(float a, float b) {  // lo16=trunc(a), hi16=trunc(b)
  return (__float_as_uint(b) & 0xffff0000u) | (__float_as_uint(a) >> 16);
}

#define MFMA(a, b, c) __builtin_amdgcn_mfma_f32_16x16x32_bf16((a), (b), (c), 0, 0, 0)

#define GLOAD_LDS16(g, l) \
  __builtin_amdgcn_global_load_lds((const __attribute__((address_space(1))) void*)(g), \
      (__attribute__((address_space(3))) void*)(l), 16, 0, 0)

// fp32 -> bf16 hi/lo planes (weights, once per launch)
__global__ __launch_bounds__(256) void split_kernel(const float* __restrict__ src,
    short* __restrict__ hi, short* __restrict__ lo, int count4)
{
  int i = blockIdx.x * 256 + threadIdx.x;
  if (i >= count4) return;
  float4v t = ((const float4v*)src)[i];
  short4v h4, l4; short hh, ll;
  split2(t.x, hh, ll); h4.x = hh; l4.x = ll;
  split2(t.y, hh, ll); h4.y = hh; l4.y = ll;
  split2(t.z, hh, ll); h4.z = hh; l4.z = ll;
  split2(t.w, hh, ll); h4.w = hh; l4.w = ll;
  ((short4v*)hi)[i] = h4;
  ((short4v*)lo)[i] = l4;
}

__global__ __launch_bounds__(256) void inv_kernel(const float* __restrict__ sums,
    float* __restrict__ inv)
{
  int i = blockIdx.x * 256 + threadIdx.x;
  if (i < B_ * E_) inv[i] = 1.0f / sums[i];
}

// C[m][n] = sum_k A[m][k]*W[n][k] + bias[n], split precision (3 products)
// AMODE 0: A fp32; AMODE 1: A fp32 scaled by inv[b*768+k] (zeros where uncovered)
// W: pre-split bf16 hi/lo planes, staged via global_load_lds into swizzled unpadded LDS
template<int AMODE, bool OUT_PAIR>
__global__ __launch_bounds__(256) void gemm_xwT(const float* __restrict__ Ap,
    const float* __restrict__ inv, const short* __restrict__ Wh,
    const short* __restrict__ Wl, const float* __restrict__ bias,
    void* __restrict__ OutH, short* __restrict__ OutL)
{
  __shared__ short Ash[128 * 40], Asl[128 * 40];   // padded
  __shared__ short Wsh[128 * 32], Wsl[128 * 32];   // unpadded, chunk-swizzled
  const int tid = threadIdx.x;
  const int m0 = blockIdx.y * 128;
  const int n0 = blockIdx.x * 128;
  const int w = tid >> 6, lane = tid & 63, quad = lane >> 4, l16 = lane & 15;
  const int wr = w >> 1, wc = w & 1;
  const int cq = (l16 >> 1) & 3;                   // read-side swizzle

  float4v acc[4][4];
#pragma unroll
  for (int a = 0; a < 4; ++a)
#pragma unroll
    for (int c = 0; c < 4; ++c) acc[a][c] = (float4v)0.0f;

  for (int kt = 0; kt < 24; ++kt) {
    const int k0 = kt * 32;
    // W staging: async DMA, 2 chunks per lane per plane (512 slots of 16B each)
#pragma unroll
    for (int i = 0; i < 2; ++i) {
      int slot = w * 128 + i * 64 + lane;
      int row = slot >> 2, cs = slot & 3;
      int cl = cs ^ ((row >> 1) & 3);
      size_t go = (size_t)(n0 + row) * E_ + k0 + cl * 8;
      GLOAD_LDS16(Wh + go, &Wsh[slot * 8]);
      GLOAD_LDS16(Wl + go, &Wsl[slot * 8]);
    }
    // A staging: fp32 load + rn1 split, packed b32 writes
#pragma unroll
    for (int p = 0; p < 4; ++p) {
      int idx = tid + p * 256;          // 1024 tasks: 128 rows x 8 chunks of 4
      int row = idx >> 3, c4 = (idx & 7) * 4;
      float4v t = *(const float4v*)(Ap + (size_t)(m0 + row) * E_ + k0 + c4);
      if constexpr (AMODE == 1) {
        float4v iv = *(const float4v*)(inv + (m0 >> 13) * E_ + k0 + c4);
        t *= iv;
      }
      unsigned h0, h1, h2, h3; float l0, l1, l2, l3;
      split_rn1(t.x, h0, l0); split_rn1(t.y, h1, l1);
      split_rn1(t.z, h2, l2); split_rn1(t.w, h3, l3);
      uint2v hp, lp;
      hp.x = h0 | (h1 << 16); hp.y = h2 | (h3 << 16);
      lp.x = pack_trunc(l0, l1); lp.y = pack_trunc(l2, l3);
      *(uint2v*)&Ash[row * 40 + c4] = hp;
      *(uint2v*)&Asl[row * 40 + c4] = lp;
    }
    __syncthreads();

    short8 afh[4], afl[4], bfh[4], bfl[4];
#pragma unroll
    for (int rt = 0; rt < 4; ++rt) {
      afh[rt] = *(const short8*)&Ash[(wr * 64 + rt * 16 + l16) * 40 + quad * 8];
      afl[rt] = *(const short8*)&Asl[(wr * 64 + rt * 16 + l16) * 40 + quad * 8];
    }
#pragma unroll
    for (int ct = 0; ct < 4; ++ct) {
      int wrow = (wc * 64 + ct * 16 + l16) * 32 + (quad ^ cq) * 8;
      bfh[ct] = *(const short8*)&Wsh[wrow];
      bfl[ct] = *(const short8*)&Wsl[wrow];
    }
#pragma unroll
    for (int rt = 0; rt < 4; ++rt)
#pragma unroll
      for (int ct = 0; ct < 4; ++ct) {
        float4v a = acc[rt][ct];
        a = MFMA(afh[rt], bfh[ct], a);
        a = MFMA(afh[rt], bfl[ct], a);
        a = MFMA(afl[rt], bfh[ct], a);
        acc[rt][ct] = a;
      }
    __syncthreads();
  }

#pragma unroll
  for (int ct = 0; ct < 4; ++ct) {
    int n = n0 + wc * 64 + ct * 16 + l16;
    float bv = bias[n];
#pragma unroll
    for (int rt = 0; rt < 4; ++rt) {
#pragma unroll
      for (int i = 0; i < 4; ++i) {
        int m = m0 + wr * 64 + rt * 16 + quad * 4 + i;
        float v = acc[rt][ct][i] + bv;
        if constexpr (OUT_PAIR) {
          short hh, ll; split2(v, hh, ll);
          ((short*)OutH)[(size_t)m * E_ + n] = hh;
          OutL[(size_t)m * E_ + n] = ll;
        } else {
          ((float*)OutH)[(size_t)m * E_ + n] = v;
        }
      }
    }
  }
}

// cumulative jj-extent offset per head: g=h>>2, ext=8192>>g
__device__ __host__ inline int hoff_of(int g, int hg) {
  return g == 0 ? hg * 8192 : (g == 1 ? 32768 + hg * 4096 : 49152 + hg * 2048);
}

// V [b][n][h][d] hi/lo -> gathered transposed Vg [b][h][d][jj]
__global__ __launch_bounds__(256) void transpose_v(const short* __restrict__ vh,
    const short* __restrict__ vl, short* __restrict__ vgh, short* __restrict__ vgl)
{
  __shared__ short Lh[64 * 68], Ll[64 * 68];
  int bid = blockIdx.x;
  int b = 0;
  if (bid >= 896) { b = 1; bid -= 896; }
  int g, hg, tile;
  if (bid < 512)      { g = 0; hg = bid >> 7; tile = bid & 127; }
  else if (bid < 768) { g = 1; hg = (bid - 512) >> 6; tile = (bid - 512) & 63; }
  else                { g = 2; hg = (bid - 768) >> 5; tile = (bid - 768) & 31; }
  const int h = g * 4 + hg, r = 1 << g, off = g;
  const int ext = 8192 >> g;
  const int jj0 = tile * 64, seg = jj0 >> 11, j0 = jj0 & 2047;
  const int n0 = seg * (2048 << g) + off + j0 * r;
  const int tid = threadIdx.x;

#pragma unroll
  for (int p = 0; p < 2; ++p) {
    int c = tid + p * 256;
    int jr = c >> 3, c8 = (c & 7) * 8;
    size_t gsrc = ((size_t)(b * N_ + n0 + jr * r) * H_ + h) * D_ + c8;
    *(short8*)&Lh[jr * 68 + c8] = *(const short8*)(vh + gsrc);
    *(short8*)&Ll[jr * 68 + c8] = *(const short8*)(vl + gsrc);
  }
  __syncthreads();
  size_t basebh = ((size_t)b * 57344 + hoff_of(g, hg)) * 64;
#pragma unroll
  for (int p = 0; p < 2; ++p) {
    int c = tid + p * 256;
    int dd = c >> 3, jc = (c & 7) * 8;
    short8 oh, ol;
#pragma unroll
    for (int u = 0; u < 8; ++u) {
      oh[u] = Lh[(jc + u) * 68 + dd];
      ol[u] = Ll[(jc + u) * 68 + dd];
    }
    size_t gdst = basebh + (size_t)dd * ext + jj0 + jc;
    *(short8*)(vgh + gdst) = oh;
    *(short8*)(vgl + gdst) = ol;
  }
}

// Flash attention, S^T = K*Q^T / O^T = V^T*P^T, split precision.
__global__ __launch_bounds__(256) void attn_kernel(
    const short* __restrict__ qh, const short* __restrict__ ql,
    const short* __restrict__ kh, const short* __restrict__ kl,
    const short* __restrict__ vgh, const short* __restrict__ vgl,
    float* __restrict__ attn_out, float* __restrict__ sums)
{
  __shared__ short Ksh[32 * 72], Ksl[32 * 72];
  __shared__ short Vth[64 * 40], Vtl[64 * 40];
  __shared__ short Psh[4][32 * 40], Psl[4][32 * 40];

  int bid = blockIdx.x;
  int g, t;
  if (bid < 512)      { g = 0; t = bid; }
  else if (bid < 768) { g = 1; t = bid - 512; }
  else                { g = 2; t = bid - 768; }
  const int qtile = t & 15; t >>= 4;
  const int hg = t & 3; t >>= 2;
  const int nseg = 4 >> g;
  const int seg = t & (nseg - 1);
  const int b = t / nseg;
  const int r = 1 << g;
  const int off = g;
  const int h = g * 4 + hg;
  const int segbase = seg * (2048 << g);
  const int ext = 8192 >> g;

  const int tid = threadIdx.x;
  const int w = tid >> 6, lane = tid & 63, quad = lane >> 4, l16 = lane & 15;

  const size_t vbase = ((size_t)b * 57344 + hoff_of(g, hg)) * 64 + (size_t)seg * 2048;

  // zero-fill uncovered attn slots for this block's q-range (siblings in residue)
  if (g > 0) {
#pragma unroll
    for (int res0 = 1; res0 < 4; ++res0) {
      if (res0 >= r) break;
      int res = (off + res0) & (r - 1);
      for (int c = 0; c < 8; ++c) {
        int idx = tid + c * 256;          // 2048 tasks: 128 j x 16 float4
        int jl = idx >> 4, d0 = (idx & 15) * 4;
        int pos = segbase + res + (qtile * 128 + jl) * r;
        *(float4v*)(attn_out + ((size_t)(b * N_ + pos) * H_ + h) * D_ + d0) = (float4v)0.f;
      }
    }
  }

  // Q B-frags (n = l16 = q, k = quad*8+j [+32*ks])
  short8 qfh[2][2], qfl[2][2];
#pragma unroll
  for (int qt = 0; qt < 2; ++qt) {
    int j = qtile * 128 + w * 32 + qt * 16 + l16;
    int pos = segbase + off + j * r;
    size_t base = ((size_t)(b * N_ + pos) * H_ + h) * D_;
#pragma unroll
    for (int ks = 0; ks < 2; ++ks) {
      qfh[qt][ks] = *(const short8*)(qh + base + ks * 32 + quad * 8);
      qfl[qt][ks] = *(const short8*)(ql + base + ks * 32 + quad * 8);
    }
  }

  float4v o[4][2];                      // [dt][qt]
  float mrow[2], lrow[2];
#pragma unroll
  for (int dt = 0; dt < 4; ++dt)
#pragma unroll
    for (int qt = 0; qt < 2; ++qt) o[dt][qt] = (float4v)0.0f;
  mrow[0] = mrow[1] = -INFINITY;
  lrow[0] = lrow[1] = 0.f;

  for (int kt = 0; kt < 64; ++kt) {
    {
      int row = tid >> 3, c8 = (tid & 7) * 8;
      int posk = segbase + off + (kt * 32 + row) * r;
      size_t gb = ((size_t)(b * N_ + posk) * H_ + h) * D_ + c8;
      *(short8*)&Ksh[row * 72 + c8] = *(const short8*)(kh + gb);
      *(short8*)&Ksl[row * 72 + c8] = *(const short8*)(kl + gb);
      int dd = tid >> 2, kvc = (tid & 3) * 8;
      size_t vb = vbase + (size_t)dd * ext + kt * 32 + kvc;
      *(short8*)&Vth[dd * 40 + kvc] = *(const short8*)(vgh + vb);
      *(short8*)&Vtl[dd * 40 + kvc] = *(const short8*)(vgl + vb);
    }
    __syncthreads();

    // S^T = K*Q^T (3-product split)
    float4v sc[2][2];
#pragma unroll
    for (int kvt = 0; kvt < 2; ++kvt) {
      const int kb = (kvt * 16 + l16) * 72 + quad * 8;
      short8 ah0 = *(const short8*)&Ksh[kb];
      short8 ah1 = *(const short8*)&Ksh[kb + 32];
      short8 al0 = *(const short8*)&Ksl[kb];
      short8 al1 = *(const short8*)&Ksl[kb + 32];
#pragma unroll
      for (int qt = 0; qt < 2; ++qt) {
        float4v a = (float4v)0.0f;
        a = MFMA(ah0, qfh[qt][0], a); a = MFMA(ah1, qfh[qt][1], a);
        a = MFMA(ah0, qfl[qt][0], a); a = MFMA(ah1, qfl[qt][1], a);
        a = MFMA(al0, qfh[qt][0], a); a = MFMA(al1, qfh[qt][1], a);
        sc[qt][kvt] = a * 0.125f;       // 1/sqrt(64)
      }
    }

    // online softmax, q = l16
#pragma unroll
    for (int qt = 0; qt < 2; ++qt) {
      float mx = sc[qt][0][0];
#pragma unroll
      for (int kvt = 0; kvt < 2; ++kvt)
#pragma unroll
        for (int i = 0; i < 4; ++i) mx = fmaxf(mx, sc[qt][kvt][i]);
      mx = fmaxf(mx, __shfl_xor(mx, 16, 64));
      mx = fmaxf(mx, __shfl_xor(mx, 32, 64));
      if (__any(mx > mrow[qt])) {
        float mnew = fmaxf(mrow[qt], mx);
        float alpha = __expf(mrow[qt] - mnew);
        mrow[qt] = mnew;
        lrow[qt] *= alpha;
#pragma unroll
        for (int dt = 0; dt < 4; ++dt) o[dt][qt] *= alpha;
      }
      float rs = 0.f;
#pragma unroll
      for (int kvt = 0; kvt < 2; ++kvt)
#pragma unroll
        for (int i = 0; i < 4; ++i) {
          float p = __expf(sc[qt][kvt][i] - mrow[qt]);
          sc[qt][kvt][i] = p;
          rs += p;
        }
      rs += __shfl_xor(rs, 16, 64);
      rs += __shfl_xor(rs, 32, 64);
      lrow[qt] += rs;

      // P^T -> Ps, truncation split, packed b32 writes (safe: errors cancel in PV sum)
#pragma unroll
      for (int kvt = 0; kvt < 2; ++kvt)
#pragma unroll
        for (int c = 0; c < 2; ++c) {
          float pa = sc[qt][kvt][2 * c], pb = sc[qt][kvt][2 * c + 1];
          unsigned ua = __float_as_uint(pa), ub = __float_as_uint(pb);
          float la = pa - __uint_as_float(ua & 0xffff0000u);
          float lb = pb - __uint_as_float(ub & 0xffff0000u);
          int ad = (qt * 16 + l16) * 40 + kvt * 16 + quad * 4 + 2 * c;
          *(unsigned*)&Psh[w][ad] = (ub & 0xffff0000u) | (ua >> 16);
          *(unsigned*)&Psl[w][ad] = pack_trunc(la, lb);
        }
    }

    // O^T += V^T * P^T
    short8 pfh[2], pfl[2];
#pragma unroll
    for (int qt = 0; qt < 2; ++qt) {
      pfh[qt] = *(const short8*)&Psh[w][(qt * 16 + l16) * 40 + quad * 8];
      pfl[qt] = *(const short8*)&Psl[w][(qt * 16 + l16) * 40 + quad * 8];
    }
#pragma unroll
    for (int dt = 0; dt < 4; ++dt) {
      short8 vfh = *(const short8*)&Vth[(dt * 16 + l16) * 40 + quad * 8];
      short8 vfl = *(const short8*)&Vtl[(dt * 16 + l16) * 40 + quad * 8];
#pragma unroll
      for (int qt = 0; qt < 2; ++qt) {
        float4v a = o[dt][qt];
        a = MFMA(vfh, pfh[qt], a);
        a = MFMA(vfh, pfl[qt], a);
        a = MFMA(vfl, pfh[qt], a);
        o[dt][qt] = a;
      }
    }
    __syncthreads();
  }

  // epilogue
  float4v sacc[4];
#pragma unroll
  for (int dt = 0; dt < 4; ++dt) sacc[dt] = (float4v)0.0f;
#pragma unroll
  for (int qt = 0; qt < 2; ++qt) {
    float inv_l = 1.0f / lrow[qt];
    int j = qtile * 128 + w * 32 + qt * 16 + l16;
    int pos = segbase + off + j * r;
    float* dst = attn_out + ((size_t)(b * N_ + pos) * H_ + h) * D_;
#pragma unroll
    for (int dt = 0; dt < 4; ++dt) {
      float4v v = o[dt][qt] * inv_l;
      *(float4v*)(dst + dt * 16 + quad * 4) = v;
      sacc[dt] += v;
    }
  }
#pragma unroll
  for (int dt = 0; dt < 4; ++dt) {
#pragma unroll
    for (int i = 0; i < 4; ++i) {
      float x = sacc[dt][i];
      x += __shfl_xor(x, 1, 64);
      x += __shfl_xor(x, 2, 64);
      x += __shfl_xor(x, 4, 64);
      x += __shfl_xor(x, 8, 64);
      if (l16 == 0)
        atomicAdd(&sums[(size_t)b * E_ + h * D_ + dt * 16 + quad * 4 + i], x);
    }
  }
}

extern "C" void kernel_launch(void* const* d_in, const int* in_sizes, int n_in,
                              void* d_out, int out_size, void* d_ws, size_t ws_size,
                              hipStream_t stream)
{
  const float* query = (const float*)d_in[0];
  const float* key_  = (const float*)d_in[1];
  const float* value = (const float*)d_in[2];
  const float* Wq = (const float*)d_in[3];
  const float* bq = (const float*)d_in[4];
  const float* Wk = (const float*)d_in[5];
  const float* bk = (const float*)d_in[6];
  const float* Wv = (const float*)d_in[7];
  const float* bv = (const float*)d_in[8];
  const float* Wo = (const float*)d_in[9];
  const float* bo = (const float*)d_in[10];

  char* ws = (char*)d_ws;
  const size_t szbf = (size_t)M_ * E_ * 2;           // 25,165,824
  const size_t szvg = (size_t)2 * 57344 * 64 * 2;    // 14,680,064
  const size_t szw  = (size_t)E_ * E_ * 2;           // 1,179,648
  short* qh_ = (short*)(ws);
  short* ql_ = (short*)(ws + 1 * szbf);
  short* kh_ = (short*)(ws + 2 * szbf);
  short* kl_ = (short*)(ws + 3 * szbf);
  short* vh_ = (short*)(ws + 4 * szbf);
  short* vl_ = (short*)(ws + 5 * szbf);
  short* vgh = (short*)(ws + 6 * szbf);
  short* vgl = (short*)(ws + 6 * szbf + szvg);
  short* wsp = (short*)(ws + 6 * szbf + 2 * szvg);   // 8 planes of szw
  short* wqh = wsp + 0 * (szw / 2), *wql = wsp + 1 * (szw / 2);
  short* wkh = wsp + 2 * (szw / 2), *wkl = wsp + 3 * (szw / 2);
  short* wvh = wsp + 4 * (szw / 2), *wvl = wsp + 5 * (szw / 2);
  short* woh = wsp + 6 * (szw / 2), *wol = wsp + 7 * (szw / 2);
  float* sums = (float*)(ws + 6 * szbf + 2 * szvg + 8 * szw);
  float* attn = (float*)(ws + 4 * szbf);             // overlays vh/vl (dead after transpose)
  float* inv  = (float*)qh_;                         // q dead after attn_kernel

  hipMemsetAsync(sums, 0, (size_t)B_ * E_ * sizeof(float), stream);

  const int wc4 = E_ * E_ / 4;                       // 147456
  split_kernel<<<(wc4 + 255) / 256, 256, 0, stream>>>(Wq, wqh, wql, wc4);
  split_kernel<<<(wc4 + 255) / 256, 256, 0, stream>>>(Wk, wkh, wkl, wc4);
  split_kernel<<<(wc4 + 255) / 256, 256, 0, stream>>>(Wv, wvh, wvl, wc4);
  split_kernel<<<(wc4 + 255) / 256, 256, 0, stream>>>(Wo, woh, wol, wc4);

  dim3 gg(6, 128), gb(256);
  gemm_xwT<0, true><<<gg, gb, 0, stream>>>(query, nullptr, wqh, wql, bq, qh_, ql_);
  gemm_xwT<0, true><<<gg, gb, 0, stream>>>(key_,  nullptr, wkh, wkl, bk, kh_, kl_);
  gemm_xwT<0, true><<<gg, gb, 0, stream>>>(value, nullptr, wvh, wvl, bv, vh_, vl_);
  transpose_v<<<1792, 256, 0, stream>>>(vh_, vl_, vgh, vgl);
  attn_kernel<<<896, 256, 0, stream>>>(qh_, ql_, kh_, kl_, vgh, vgl, attn, sums);
  inv_kernel<<<6, 256, 0, stream>>>(sums, inv);
  gemm_xwT<1, false><<<gg, gb, 0, stream>>>(attn, inv, woh, wol, bo, d_out, nullptr);
}

// Round 5
// 877.342 us; speedup vs baseline: 1.5947x; 1.0105x over previous
//
#include <hip/hip_runtime.h>
#include <hip/hip_bf16.h>
#include <cmath>
#include <cstdint>

#define B_ 2
#define N_ 8192
#define H_ 12
#define D_ 64
#define E_ 768
#define M_ (B_*N_)   // 16384

typedef __attribute__((ext_vector_type(8))) short short8;
typedef __attribute__((ext_vector_type(4))) short short4v;
typedef __attribute__((ext_vector_type(4))) float float4v;

__device__ inline short f2b(float f) {
  union { float f; unsigned u; } x; x.f = f;
  unsigned r = (x.u + 0x7fffu + ((x.u >> 16) & 1u)) >> 16;
  return (short)r;
}
__device__ inline float b2f(short s) {
  union { unsigned u; float f; } x; x.u = ((unsigned)(unsigned short)s) << 16;
  return x.f;
}
// round-to-nearest hi + bf16 lo: residual ~2^-18 relative
__device__ inline void split2(float f, short& h, short& l) {
  h = f2b(f);
  l = f2b(f - b2f(h));
}
__device__ inline unsigned pack_trunc(float a, float b) {  // lo16=trunc(a), hi16=trunc(b)
  return (__float_as_uint(b) & 0xffff0000u) | (__float_as_uint(a) >> 16);
}

#define MFMA(a, b, c) __builtin_amdgcn_mfma_f32_16x16x32_bf16((a), (b), (c), 0, 0, 0)

#define GLOAD_LDS16(g, l) \
  __builtin_amdgcn_global_load_lds((const __attribute__((address_space(1))) void*)(g), \
      (__attribute__((address_space(3))) void*)(l), 16, 0, 0)

// fp32 -> bf16 hi/lo planes
__global__ __launch_bounds__(256) void split_kernel(const float* __restrict__ src,
    short* __restrict__ hi, short* __restrict__ lo, int count4)
{
  int i = blockIdx.x * 256 + threadIdx.x;
  if (i >= count4) return;
  float4v t = ((const float4v*)src)[i];
  short4v h4, l4; short hh, ll;
  split2(t.x, hh, ll); h4.x = hh; l4.x = ll;
  split2(t.y, hh, ll); h4.y = hh; l4.y = ll;
  split2(t.z, hh, ll); h4.z = hh; l4.z = ll;
  split2(t.w, hh, ll); h4.w = hh; l4.w = ll;
  ((short4v*)hi)[i] = h4;
  ((short4v*)lo)[i] = l4;
}

// all 4 weight matrices in one launch (blockIdx.y selects)
__global__ __launch_bounds__(256) void split_w4(
    const float* __restrict__ w0, const float* __restrict__ w1,
    const float* __restrict__ w2, const float* __restrict__ w3,
    short* __restrict__ planes)   // 8 planes of E*E shorts: h0,l0,h1,l1,...
{
  int which = blockIdx.y;
  const float* src = which == 0 ? w0 : which == 1 ? w1 : which == 2 ? w2 : w3;
  short* hi = planes + (size_t)(2 * which) * (E_ * E_);
  short* lo = planes + (size_t)(2 * which + 1) * (E_ * E_);
  int i = blockIdx.x * 256 + threadIdx.x;
  if (i >= E_ * E_ / 4) return;
  float4v t = ((const float4v*)src)[i];
  short4v h4, l4; short hh, ll;
  split2(t.x, hh, ll); h4.x = hh; l4.x = ll;
  split2(t.y, hh, ll); h4.y = hh; l4.y = ll;
  split2(t.z, hh, ll); h4.z = hh; l4.z = ll;
  split2(t.w, hh, ll); h4.w = hh; l4.w = ll;
  ((short4v*)hi)[i] = h4;
  ((short4v*)lo)[i] = l4;
}

__global__ __launch_bounds__(256) void inv_kernel(const float* __restrict__ sums,
    float* __restrict__ inv)
{
  int i = blockIdx.x * 256 + threadIdx.x;
  if (i < B_ * E_) inv[i] = 1.0f / sums[i];
}

// xnorm = attn[b,n,e] * inv[b,e] -> bf16 hi/lo planes
__global__ __launch_bounds__(256) void prep_out(const float* __restrict__ attn,
    const float* __restrict__ inv, short* __restrict__ xnh, short* __restrict__ xnl)
{
  size_t e4 = ((size_t)blockIdx.x * 256 + threadIdx.x) * 4;
  int e = (int)(e4 % E_);
  int b = (int)(e4 / ((size_t)E_ * N_));
  float4v a = *(const float4v*)(attn + e4);
  float4v iv = *(const float4v*)(inv + (size_t)b * E_ + e);
  a *= iv;
  short4v h4, l4; short hh, ll;
  split2(a.x, hh, ll); h4.x = hh; l4.x = ll;
  split2(a.y, hh, ll); h4.y = hh; l4.y = ll;
  split2(a.z, hh, ll); h4.z = hh; l4.z = ll;
  split2(a.w, hh, ll); h4.w = hh; l4.w = ll;
  *(short4v*)&xnh[e4] = h4;
  *(short4v*)&xnl[e4] = l4;
}

// C[m][n] = sum_k A[m][k]*W[n][k] + bias[n], 3-product split precision.
// A and W are pre-split bf16 hi/lo planes; ALL staging via global_load_lds (16B).
// LDS unpadded 128x32 tiles, XOR chunk swizzle: LDS chunk cs of row r holds
// global chunk cs ^ ((r>>1)&3); reads use (quad ^ ((l16>>1)&3)) -> conflict-free.
template<bool OUT_PAIR>
__global__ __launch_bounds__(256) void gemm_dma(
    const short* __restrict__ Ah, const short* __restrict__ Al,
    const short* __restrict__ Wh, const short* __restrict__ Wl,
    const float* __restrict__ bias, void* __restrict__ OutH, short* __restrict__ OutL)
{
  __shared__ short Ash[4096], Asl[4096], Wsh[4096], Wsl[4096];  // 128 rows x 32 k each
  const int tid = threadIdx.x;
  const int m0 = blockIdx.y * 128;
  const int n0 = blockIdx.x * 128;
  const int w = tid >> 6, lane = tid & 63, quad = lane >> 4, l16 = lane & 15;
  const int wr = w >> 1, wc = w & 1;
  const int cq = (l16 >> 1) & 3;
  const int dmarow = lane >> 2;                         // + c*16
  const int dmacc = (((lane & 3) ^ ((lane >> 3) & 3))) * 8;

  float4v acc[4][4];
#pragma unroll
  for (int a = 0; a < 4; ++a)
#pragma unroll
    for (int c = 0; c < 4; ++c) acc[a][c] = (float4v)0.0f;

  for (int kt = 0; kt < 24; ++kt) {
    const int k0 = kt * 32;
#pragma unroll
    for (int i = 0; i < 2; ++i) {
      int c = w * 2 + i;
      int ldso = c * 512 + lane * 8;                    // shorts
      size_t ga = (size_t)(m0 + c * 16 + dmarow) * E_ + k0 + dmacc;
      size_t gw = (size_t)(n0 + c * 16 + dmarow) * E_ + k0 + dmacc;
      GLOAD_LDS16(Ah + ga, &Ash[ldso]);
      GLOAD_LDS16(Al + ga, &Asl[ldso]);
      GLOAD_LDS16(Wh + gw, &Wsh[ldso]);
      GLOAD_LDS16(Wl + gw, &Wsl[ldso]);
    }
    __syncthreads();

    short8 afh[4], afl[4], bfh[4], bfl[4];
#pragma unroll
    for (int rt = 0; rt < 4; ++rt) {
      int ao = (wr * 64 + rt * 16 + l16) * 32 + (quad ^ cq) * 8;
      afh[rt] = *(const short8*)&Ash[ao];
      afl[rt] = *(const short8*)&Asl[ao];
      int wo = (wc * 64 + rt * 16 + l16) * 32 + (quad ^ cq) * 8;
      bfh[rt] = *(const short8*)&Wsh[wo];
      bfl[rt] = *(const short8*)&Wsl[wo];
    }
#pragma unroll
    for (int rt = 0; rt < 4; ++rt)
#pragma unroll
      for (int ct = 0; ct < 4; ++ct) {
        float4v a = acc[rt][ct];
        a = MFMA(afh[rt], bfh[ct], a);
        a = MFMA(afh[rt], bfl[ct], a);
        a = MFMA(afl[rt], bfh[ct], a);
        acc[rt][ct] = a;
      }
    __syncthreads();
  }

#pragma unroll
  for (int ct = 0; ct < 4; ++ct) {
    int n = n0 + wc * 64 + ct * 16 + l16;
    float bv = bias[n];
#pragma unroll
    for (int rt = 0; rt < 4; ++rt) {
#pragma unroll
      for (int i = 0; i < 4; ++i) {
        int m = m0 + wr * 64 + rt * 16 + quad * 4 + i;
        float v = acc[rt][ct][i] + bv;
        if constexpr (OUT_PAIR) {
          short hh, ll; split2(v, hh, ll);
          ((short*)OutH)[(size_t)m * E_ + n] = hh;
          OutL[(size_t)m * E_ + n] = ll;
        } else {
          ((float*)OutH)[(size_t)m * E_ + n] = v;
        }
      }
    }
  }
}

// cumulative jj-extent offset per head: g=h>>2, ext=8192>>g
__device__ __host__ inline int hoff_of(int g, int hg) {
  return g == 0 ? hg * 8192 : (g == 1 ? 32768 + hg * 4096 : 49152 + hg * 2048);
}

// V [b][n][h][d] hi/lo -> gathered transposed Vg [b][h][d][jj]
__global__ __launch_bounds__(256) void transpose_v(const short* __restrict__ vh,
    const short* __restrict__ vl, short* __restrict__ vgh, short* __restrict__ vgl)
{
  __shared__ short Lh[64 * 68], Ll[64 * 68];
  int bid = blockIdx.x;
  int b = 0;
  if (bid >= 896) { b = 1; bid -= 896; }
  int g, hg, tile;
  if (bid < 512)      { g = 0; hg = bid >> 7; tile = bid & 127; }
  else if (bid < 768) { g = 1; hg = (bid - 512) >> 6; tile = (bid - 512) & 63; }
  else                { g = 2; hg = (bid - 768) >> 5; tile = (bid - 768) & 31; }
  const int h = g * 4 + hg, r = 1 << g, off = g;
  const int ext = 8192 >> g;
  const int jj0 = tile * 64, seg = jj0 >> 11, j0 = jj0 & 2047;
  const int n0 = seg * (2048 << g) + off + j0 * r;
  const int tid = threadIdx.x;

#pragma unroll
  for (int p = 0; p < 2; ++p) {
    int c = tid + p * 256;
    int jr = c >> 3, c8 = (c & 7) * 8;
    size_t gsrc = ((size_t)(b * N_ + n0 + jr * r) * H_ + h) * D_ + c8;
    *(short8*)&Lh[jr * 68 + c8] = *(const short8*)(vh + gsrc);
    *(short8*)&Ll[jr * 68 + c8] = *(const short8*)(vl + gsrc);
  }
  __syncthreads();
  size_t basebh = ((size_t)b * 57344 + hoff_of(g, hg)) * 64;
#pragma unroll
  for (int p = 0; p < 2; ++p) {
    int c = tid + p * 256;
    int dd = c >> 3, jc = (c & 7) * 8;
    short8 oh, ol;
#pragma unroll
    for (int u = 0; u < 8; ++u) {
      oh[u] = Lh[(jc + u) * 68 + dd];
      ol[u] = Ll[(jc + u) * 68 + dd];
    }
    size_t gdst = basebh + (size_t)dd * ext + jj0 + jc;
    *(short8*)(vgh + gdst) = oh;
    *(short8*)(vgl + gdst) = ol;
  }
}

// Flash attention, S^T = K*Q^T / O^T = V^T*P^T, split precision.
__global__ __launch_bounds__(256) void attn_kernel(
    const short* __restrict__ qh, const short* __restrict__ ql,
    const short* __restrict__ kh, const short* __restrict__ kl,
    const short* __restrict__ vgh, const short* __restrict__ vgl,
    float* __restrict__ attn_out, float* __restrict__ sums)
{
  __shared__ short Ksh[32 * 72], Ksl[32 * 72];
  __shared__ short Vth[64 * 40], Vtl[64 * 40];
  __shared__ short Psh[4][32 * 40], Psl[4][32 * 40];

  int bid = blockIdx.x;
  int g, t;
  if (bid < 512)      { g = 0; t = bid; }
  else if (bid < 768) { g = 1; t = bid - 512; }
  else                { g = 2; t = bid - 768; }
  const int qtile = t & 15; t >>= 4;
  const int hg = t & 3; t >>= 2;
  const int nseg = 4 >> g;
  const int seg = t & (nseg - 1);
  const int b = t / nseg;
  const int r = 1 << g;
  const int off = g;
  const int h = g * 4 + hg;
  const int segbase = seg * (2048 << g);
  const int ext = 8192 >> g;

  const int tid = threadIdx.x;
  const int w = tid >> 6, lane = tid & 63, quad = lane >> 4, l16 = lane & 15;

  const size_t vbase = ((size_t)b * 57344 + hoff_of(g, hg)) * 64 + (size_t)seg * 2048;

  // zero-fill uncovered attn slots for this block's q-range
  if (g > 0) {
#pragma unroll
    for (int res0 = 1; res0 < 4; ++res0) {
      if (res0 >= r) break;
      int res = (off + res0) & (r - 1);
      for (int c = 0; c < 8; ++c) {
        int idx = tid + c * 256;
        int jl = idx >> 4, d0 = (idx & 15) * 4;
        int pos = segbase + res + (qtile * 128 + jl) * r;
        *(float4v*)(attn_out + ((size_t)(b * N_ + pos) * H_ + h) * D_ + d0) = (float4v)0.f;
      }
    }
  }

  // Q B-frags (n = l16 = q, k = quad*8+j [+32*ks])
  short8 qfh[2][2], qfl[2][2];
#pragma unroll
  for (int qt = 0; qt < 2; ++qt) {
    int j = qtile * 128 + w * 32 + qt * 16 + l16;
    int pos = segbase + off + j * r;
    size_t base = ((size_t)(b * N_ + pos) * H_ + h) * D_;
#pragma unroll
    for (int ks = 0; ks < 2; ++ks) {
      qfh[qt][ks] = *(const short8*)(qh + base + ks * 32 + quad * 8);
      qfl[qt][ks] = *(const short8*)(ql + base + ks * 32 + quad * 8);
    }
  }

  float4v o[4][2];
  float mrow[2], lrow[2];
#pragma unroll
  for (int dt = 0; dt < 4; ++dt)
#pragma unroll
    for (int qt = 0; qt < 2; ++qt) o[dt][qt] = (float4v)0.0f;
  mrow[0] = mrow[1] = -INFINITY;
  lrow[0] = lrow[1] = 0.f;

  for (int kt = 0; kt < 64; ++kt) {
    {
      int row = tid >> 3, c8 = (tid & 7) * 8;
      int posk = segbase + off + (kt * 32 + row) * r;
      size_t gb = ((size_t)(b * N_ + posk) * H_ + h) * D_ + c8;
      *(short8*)&Ksh[row * 72 + c8] = *(const short8*)(kh + gb);
      *(short8*)&Ksl[row * 72 + c8] = *(const short8*)(kl + gb);
      int dd = tid >> 2, kvc = (tid & 3) * 8;
      size_t vb = vbase + (size_t)dd * ext + kt * 32 + kvc;
      *(short8*)&Vth[dd * 40 + kvc] = *(const short8*)(vgh + vb);
      *(short8*)&Vtl[dd * 40 + kvc] = *(const short8*)(vgl + vb);
    }
    __syncthreads();

    // S^T = K*Q^T (3-product split)
    float4v sc[2][2];
#pragma unroll
    for (int kvt = 0; kvt < 2; ++kvt) {
      const int kb = (kvt * 16 + l16) * 72 + quad * 8;
      short8 ah0 = *(const short8*)&Ksh[kb];
      short8 ah1 = *(const short8*)&Ksh[kb + 32];
      short8 al0 = *(const short8*)&Ksl[kb];
      short8 al1 = *(const short8*)&Ksl[kb + 32];
#pragma unroll
      for (int qt = 0; qt < 2; ++qt) {
        float4v a = (float4v)0.0f;
        a = MFMA(ah0, qfh[qt][0], a); a = MFMA(ah1, qfh[qt][1], a);
        a = MFMA(ah0, qfl[qt][0], a); a = MFMA(ah1, qfl[qt][1], a);
        a = MFMA(al0, qfh[qt][0], a); a = MFMA(al1, qfh[qt][1], a);
        sc[qt][kvt] = a * 0.125f;
      }
    }

    // online softmax, q = l16
#pragma unroll
    for (int qt = 0; qt < 2; ++qt) {
      float mx = sc[qt][0][0];
#pragma unroll
      for (int kvt = 0; kvt < 2; ++kvt)
#pragma unroll
        for (int i = 0; i < 4; ++i) mx = fmaxf(mx, sc[qt][kvt][i]);
      mx = fmaxf(mx, __shfl_xor(mx, 16, 64));
      mx = fmaxf(mx, __shfl_xor(mx, 32, 64));
      if (__any(mx > mrow[qt])) {
        float mnew = fmaxf(mrow[qt], mx);
        float alpha = __expf(mrow[qt] - mnew);
        mrow[qt] = mnew;
        lrow[qt] *= alpha;
#pragma unroll
        for (int dt = 0; dt < 4; ++dt) o[dt][qt] *= alpha;
      }
      float rs = 0.f;
#pragma unroll
      for (int kvt = 0; kvt < 2; ++kvt)
#pragma unroll
        for (int i = 0; i < 4; ++i) {
          float p = __expf(sc[qt][kvt][i] - mrow[qt]);
          sc[qt][kvt][i] = p;
          rs += p;
        }
      rs += __shfl_xor(rs, 16, 64);
      rs += __shfl_xor(rs, 32, 64);
      lrow[qt] += rs;

      // P^T -> Ps, truncation split, packed b32 writes
#pragma unroll
      for (int kvt = 0; kvt < 2; ++kvt)
#pragma unroll
        for (int c = 0; c < 2; ++c) {
          float pa = sc[qt][kvt][2 * c], pb = sc[qt][kvt][2 * c + 1];
          unsigned ua = __float_as_uint(pa), ub = __float_as_uint(pb);
          float la = pa - __uint_as_float(ua & 0xffff0000u);
          float lb = pb - __uint_as_float(ub & 0xffff0000u);
          int ad = (qt * 16 + l16) * 40 + kvt * 16 + quad * 4 + 2 * c;
          *(unsigned*)&Psh[w][ad] = (ub & 0xffff0000u) | (ua >> 16);
          *(unsigned*)&Psl[w][ad] = pack_trunc(la, lb);
        }
    }

    // O^T += V^T * P^T
    short8 pfh[2], pfl[2];
#pragma unroll
    for (int qt = 0; qt < 2; ++qt) {
      pfh[qt] = *(const short8*)&Psh[w][(qt * 16 + l16) * 40 + quad * 8];
      pfl[qt] = *(const short8*)&Psl[w][(qt * 16 + l16) * 40 + quad * 8];
    }
#pragma unroll
    for (int dt = 0; dt < 4; ++dt) {
      short8 vfh = *(const short8*)&Vth[(dt * 16 + l16) * 40 + quad * 8];
      short8 vfl = *(const short8*)&Vtl[(dt * 16 + l16) * 40 + quad * 8];
#pragma unroll
      for (int qt = 0; qt < 2; ++qt) {
        float4v a = o[dt][qt];
        a = MFMA(vfh, pfh[qt], a);
        a = MFMA(vfh, pfl[qt], a);
        a = MFMA(vfl, pfh[qt], a);
        o[dt][qt] = a;
      }
    }
    __syncthreads();
  }

  // epilogue
  float4v sacc[4];
#pragma unroll
  for (int dt = 0; dt < 4; ++dt) sacc[dt] = (float4v)0.0f;
#pragma unroll
  for (int qt = 0; qt < 2; ++qt) {
    float inv_l = 1.0f / lrow[qt];
    int j = qtile * 128 + w * 32 + qt * 16 + l16;
    int pos = segbase + off + j * r;
    float* dst = attn_out + ((size_t)(b * N_ + pos) * H_ + h) * D_;
#pragma unroll
    for (int dt = 0; dt < 4; ++dt) {
      float4v v = o[dt][qt] * inv_l;
      *(float4v*)(dst + dt * 16 + quad * 4) = v;
      sacc[dt] += v;
    }
  }
#pragma unroll
  for (int dt = 0; dt < 4; ++dt) {
#pragma unroll
    for (int i = 0; i < 4; ++i) {
      float x = sacc[dt][i];
      x += __shfl_xor(x, 1, 64);
      x += __shfl_xor(x, 2, 64);
      x += __shfl_xor(x, 4, 64);
      x += __shfl_xor(x, 8, 64);
      if (l16 == 0)
        atomicAdd(&sums[(size_t)b * E_ + h * D_ + dt * 16 + quad * 4 + i], x);
    }
  }
}

extern "C" void kernel_launch(void* const* d_in, const int* in_sizes, int n_in,
                              void* d_out, int out_size, void* d_ws, size_t ws_size,
                              hipStream_t stream)
{
  const float* query = (const float*)d_in[0];
  const float* key_  = (const float*)d_in[1];
  const float* value = (const float*)d_in[2];
  const float* Wq = (const float*)d_in[3];
  const float* bq = (const float*)d_in[4];
  const float* Wk = (const float*)d_in[5];
  const float* bk = (const float*)d_in[6];
  const float* Wv = (const float*)d_in[7];
  const float* bv = (const float*)d_in[8];
  const float* Wo = (const float*)d_in[9];
  const float* bo = (const float*)d_in[10];

  char* ws = (char*)d_ws;
  const size_t szbf = (size_t)M_ * E_ * 2;           // 25,165,824
  const size_t szvg = (size_t)2 * 57344 * 64 * 2;    // 14,680,064
  const size_t szw  = (size_t)E_ * E_ * 2;           // 1,179,648
  short* qh_ = (short*)(ws);
  short* ql_ = (short*)(ws + 1 * szbf);
  short* kh_ = (short*)(ws + 2 * szbf);
  short* kl_ = (short*)(ws + 3 * szbf);
  short* vh_ = (short*)(ws + 4 * szbf);
  short* vl_ = (short*)(ws + 5 * szbf);
  // [6szbf, 8szbf): input-split scratch (serial q,k,v), later overlaid by vg
  short* ish = (short*)(ws + 6 * szbf);
  short* isl = (short*)(ws + 7 * szbf);
  short* vgh = (short*)(ws + 6 * szbf);
  short* vgl = (short*)(ws + 6 * szbf + szvg);
  short* wsp = (short*)(ws + 8 * szbf);              // 8 weight planes
  float* sums = (float*)(ws + 8 * szbf + 8 * szw);
  float* attn = (float*)(ws + 4 * szbf);             // overlays vh/vl (dead after transpose)
  float* inv  = (float*)qh_;                         // q dead after attn_kernel
  short* xnh = kh_;                                  // k dead after attn_kernel
  short* xnl = kl_;
  short* wqh = wsp + 0 * (szw / 2), *wql = wsp + 1 * (szw / 2);
  short* wkh = wsp + 2 * (szw / 2), *wkl = wsp + 3 * (szw / 2);
  short* wvh = wsp + 4 * (szw / 2), *wvl = wsp + 5 * (szw / 2);
  short* woh = wsp + 6 * (szw / 2), *wol = wsp + 7 * (szw / 2);

  hipMemsetAsync(sums, 0, (size_t)B_ * E_ * sizeof(float), stream);

  split_w4<<<dim3(576, 4), 256, 0, stream>>>(Wq, Wk, Wv, Wo, wsp);

  const int ac4 = M_ * E_ / 4;                       // 3,145,728 -> 12288 blocks
  dim3 gg(6, 128), gb(256);
  split_kernel<<<12288, 256, 0, stream>>>(query, ish, isl, ac4);
  gemm_dma<true><<<gg, gb, 0, stream>>>(ish, isl, wqh, wql, bq, qh_, ql_);
  split_kernel<<<12288, 256, 0, stream>>>(key_, ish, isl, ac4);
  gemm_dma<true><<<gg, gb, 0, stream>>>(ish, isl, wkh, wkl, bk, kh_, kl_);
  split_kernel<<<12288, 256, 0, stream>>>(value, ish, isl, ac4);
  gemm_dma<true><<<gg, gb, 0, stream>>>(ish, isl, wvh, wvl, bv, vh_, vl_);

  transpose_v<<<1792, 256, 0, stream>>>(vh_, vl_, vgh, vgl);
  attn_kernel<<<896, 256, 0, stream>>>(qh_, ql_, kh_, kl_, vgh, vgl, attn, sums);
  inv_kernel<<<6, 256, 0, stream>>>(sums, inv);
  prep_out<<<12288, 256, 0, stream>>>(attn, inv, xnh, xnl);
  gemm_dma<false><<<gg, gb, 0, stream>>>(xnh, xnl, woh, wol, bo, d_out, nullptr);
}